// Round 7
// baseline (354.901 us; speedup 1.0000x reference)
//
#include <hip/hip_runtime.h>
#include <math.h>
#include <stdint.h>

#define LN_EPS 1e-5f
#define GRP_SHIFT 7           // 128 nodes per bucket
#define MAXBUK 1024           // N <= 131072
#define PCHUNK 4096           // edges per partition block (1024 threads x 4)

// ---------- bf16 helpers (RNE) ----------
__device__ __forceinline__ unsigned short f2bf(float f) {
  unsigned int u = __float_as_uint(f);
  unsigned int r = u + 0x7fffu + ((u >> 16) & 1u);
  return (unsigned short)(r >> 16);
}
__device__ __forceinline__ float bfLo(unsigned v) { return __uint_as_float(v << 16); }
__device__ __forceinline__ float bfHi(unsigned v) { return __uint_as_float(v & 0xffff0000u); }

// ---------- CSR build, bucketed counting sort ----------
__global__ __launch_bounds__(1024) void k_bucket_count(const int* __restrict__ dst,
                                                       int* __restrict__ bcnt, int E, int NB) {
  __shared__ int hist[MAXBUK];
  int t = threadIdx.x;
  for (int i = t; i < NB; i += 1024) hist[i] = 0;
  __syncthreads();
  int e0 = blockIdx.x * PCHUNK;
  int e1 = min(e0 + PCHUNK, E);
#pragma unroll
  for (int j = 0; j < 4; ++j) {
    int i = e0 + t + j * 1024;
    if (i < e1) atomicAdd(&hist[dst[i] >> GRP_SHIFT], 1);
  }
  __syncthreads();
  for (int i = t; i < NB; i += 1024)
    if (hist[i]) atomicAdd(&bcnt[i], hist[i]);
}

__global__ __launch_bounds__(256) void k_bucket_scan(const int* __restrict__ cnt,
                                                     int* __restrict__ base,
                                                     int* __restrict__ cur, int NB) {
  __shared__ int ts[256];
  int t = threadIdx.x;
  int v[4];
  int s = 0;
#pragma unroll
  for (int j = 0; j < 4; ++j) { int i = t * 4 + j; v[j] = (i < NB) ? cnt[i] : 0; s += v[j]; }
  ts[t] = s;
  __syncthreads();
  for (int o = 1; o < 256; o <<= 1) {
    int x = (t >= o) ? ts[t - o] : 0;
    __syncthreads();
    ts[t] += x;
    __syncthreads();
  }
  int run = ts[t] - s;
#pragma unroll
  for (int j = 0; j < 4; ++j) {
    int i = t * 4 + j;
    if (i < NB) { base[i] = run; cur[i] = run; }
    run += v[j];
  }
  if (t == 255) base[NB] = run;  // == E
}

// partition edges into per-bucket regions; payload packed (src<<7)|dst_local (N < 2^25).
// rank within (block,bucket) captured from the first histogram atomic -> single LDS pass.
__global__ __launch_bounds__(1024) void k_partition(const int* __restrict__ src,
                                                    const int* __restrict__ dst,
                                                    int* __restrict__ bcur,
                                                    unsigned* __restrict__ pairs, int E, int NB) {
  __shared__ int hist[MAXBUK];
  __shared__ int base[MAXBUK];
  int t = threadIdx.x;
  for (int i = t; i < NB; i += 1024) hist[i] = 0;
  __syncthreads();
  int e0 = blockIdx.x * PCHUNK;
  int e1 = min(e0 + PCHUNK, E);
  int sv[4], dv[4], rk[4];
#pragma unroll
  for (int j = 0; j < 4; ++j) {
    int i = e0 + t + j * 1024;
    if (i < e1) {
      sv[j] = src[i];
      dv[j] = dst[i];
      rk[j] = atomicAdd(&hist[dv[j] >> GRP_SHIFT], 1);
    } else {
      dv[j] = -1;
    }
  }
  __syncthreads();
  for (int i = t; i < NB; i += 1024) {
    int c = hist[i];
    base[i] = c ? atomicAdd(&bcur[i], c) : 0;
  }
  __syncthreads();
#pragma unroll
  for (int j = 0; j < 4; ++j) {
    if (dv[j] >= 0) {
      int b = dv[j] >> GRP_SHIFT;
      pairs[base[b] + rk[j]] = ((unsigned)sv[j] << GRP_SHIFT) | (unsigned)(dv[j] & 127);
    }
  }
}

__global__ __launch_bounds__(256) void k_bucket_place(const unsigned* __restrict__ pairs,
                                                      const int* __restrict__ bbase,
                                                      int* __restrict__ offsets,
                                                      float* __restrict__ dinv,
                                                      int* __restrict__ csr, int N, int E) {
  __shared__ int cnt[128];
  __shared__ int sc[128];
  int t = threadIdx.x;
  int b = blockIdx.x;
  int node0 = b << GRP_SHIFT;
  if (t < 128) cnt[t] = 0;
  int beg = bbase[b], end = bbase[b + 1];
  if (b == 0 && t == 0) offsets[N] = E;
  __syncthreads();
  for (int i = beg + t; i < end; i += 256) atomicAdd(&cnt[pairs[i] & 127u], 1);
  __syncthreads();
  if (t < 128) sc[t] = cnt[t];
  __syncthreads();
  for (int o = 1; o < 128; o <<= 1) {
    int x = (t < 128 && t >= o) ? sc[t - o] : 0;
    __syncthreads();
    if (t < 128) sc[t] += x;
    __syncthreads();
  }
  if (t < 128) {
    int excl = sc[t] - cnt[t];
    int node = node0 + t;
    if (node < N) {
      offsets[node] = beg + excl;
      int d = cnt[t];
      dinv[node] = d > 0 ? rsqrtf((float)d) : 0.f;
    }
    sc[t] = beg + excl;  // becomes write cursor
  }
  __syncthreads();
  for (int i = beg + t; i < end; i += 256) {
    unsigned pk = pairs[i];
    int pos = atomicAdd(&sc[pk & 127u], 1);
    csr[pos] = (int)(pk >> GRP_SHIFT);
  }
}

// ---------- GEMM: out[m] = bf16( dinv[m] * (A[m] @ W) ), A:[M][K], W:[K][64] ----------
template <int K>
__global__ __launch_bounds__(256) void gemm_scale(const float* __restrict__ A,
                                                  const float* __restrict__ W,
                                                  const float* __restrict__ dinv,
                                                  unsigned short* __restrict__ out, int M) {
  __shared__ float xs[16][64];   // transposed A tile: xs[k][m]
  __shared__ float wsh[16][64];  // W tile: wsh[k][c]
  int t = threadIdx.x;
  int m0 = blockIdx.x * 64;
  int lm = t >> 2;
  int lk = (t & 3) << 2;
  int mr = (t & 15) << 2;
  int cc = (t >> 4) << 2;
  float acc[4][4] = {{0.f}};
  int gm = m0 + lm;
  const bool mok = gm < M;
  for (int kc = 0; kc < K; kc += 16) {
    float4 av = make_float4(0.f, 0.f, 0.f, 0.f);
    if (mok) av = *(const float4*)&A[(size_t)gm * K + kc + lk];
    float wv[4];
#pragma unroll
    for (int r = 0; r < 4; ++r) {
      int k = (t >> 6) + (r << 2);
      wv[r] = W[(size_t)(kc + k) * 64 + (t & 63)];
    }
    __syncthreads();
    xs[lk + 0][lm] = av.x;
    xs[lk + 1][lm] = av.y;
    xs[lk + 2][lm] = av.z;
    xs[lk + 3][lm] = av.w;
#pragma unroll
    for (int r = 0; r < 4; ++r) {
      int k = (t >> 6) + (r << 2);
      wsh[k][t & 63] = wv[r];
    }
    __syncthreads();
#pragma unroll
    for (int k = 0; k < 16; ++k) {
      float4 a4 = *(const float4*)&xs[k][mr];
      float4 b4 = *(const float4*)&wsh[k][cc];
      float a[4] = {a4.x, a4.y, a4.z, a4.w};
      float b[4] = {b4.x, b4.y, b4.z, b4.w};
#pragma unroll
      for (int i = 0; i < 4; ++i)
#pragma unroll
        for (int j = 0; j < 4; ++j) acc[i][j] = fmaf(a[i], b[j], acc[i][j]);
    }
  }
#pragma unroll
  for (int i = 0; i < 4; ++i) {
    int row = m0 + mr + i;
    if (row < M) {
      float sc = dinv[row];
      ushort4 o;
      o.x = f2bf(acc[i][0] * sc);
      o.y = f2bf(acc[i][1] * sc);
      o.z = f2bf(acc[i][2] * sc);
      o.w = f2bf(acc[i][3] * sc);
      *(ushort4*)&out[(size_t)row * 64 + cc] = o;
    }
  }
}

// ---------- aggregation + bias + LayerNorm + ReLU ----------
// wave per node. lane = (q, fl): q = lane>>3 handles edge (idx*8+q); fl = lane&7 owns
// features 8fl..8fl+7 (uint4 = 16B = 8 bf16 per gather) -> 8 edges per wave-load.
// Full 8-edge groups are unmasked adds; only the final partial group is predicated.
__global__ __launch_bounds__(256) void k_agg(const uint4* __restrict__ hs128,
                                             const int* __restrict__ csr,
                                             const int* __restrict__ offsets,
                                             const float* __restrict__ dinv,
                                             const float* __restrict__ b,
                                             const float* __restrict__ g,
                                             const float* __restrict__ tt,
                                             float* __restrict__ out, int n) {
  int lane = threadIdx.x & 63;
  int q = lane >> 3;
  int fl = lane & 7;
  int node = blockIdx.x * 4 + (threadIdx.x >> 6);
  if (node >= n) return;
  int beg = offsets[node];
  int end = offsets[node + 1];
  float a0 = 0.f, a1 = 0.f, a2 = 0.f, a3 = 0.f;
  float a4 = 0.f, a5 = 0.f, a6 = 0.f, a7 = 0.f;

#define G8U(idx)                                                      \
  {                                                                   \
    int sj = __shfl(cs, (idx) * 8 + q, 64);                           \
    uint4 v = hs128[(size_t)sj * 8 + fl];                             \
    a0 += bfLo(v.x); a1 += bfHi(v.x);                                 \
    a2 += bfLo(v.y); a3 += bfHi(v.y);                                 \
    a4 += bfLo(v.z); a5 += bfHi(v.z);                                 \
    a6 += bfLo(v.w); a7 += bfHi(v.w);                                 \
  }
#define G8M(idx)                                                      \
  {                                                                   \
    int sj = __shfl(cs, (idx) * 8 + q, 64);                           \
    uint4 v = hs128[(size_t)sj * 8 + fl];                             \
    float m = (e0 + (idx) * 8 + q < end) ? 1.f : 0.f;                 \
    a0 = fmaf(m, bfLo(v.x), a0); a1 = fmaf(m, bfHi(v.x), a1);         \
    a2 = fmaf(m, bfLo(v.y), a2); a3 = fmaf(m, bfHi(v.y), a3);         \
    a4 = fmaf(m, bfLo(v.z), a4); a5 = fmaf(m, bfHi(v.z), a5);         \
    a6 = fmaf(m, bfLo(v.w), a6); a7 = fmaf(m, bfHi(v.w), a7);         \
  }

  for (int e0 = beg; e0 < end; e0 += 64) {
    int cs = csr[min(e0 + lane, end - 1)];  // 64 edge indices, one coalesced load
    int rem = end - e0;                     // wave-uniform
    if (rem >= 64) {
      G8U(0) G8U(1) G8U(2) G8U(3) G8U(4) G8U(5) G8U(6) G8U(7)
    } else {
      int nf = rem >> 3;                    // full 8-edge groups
      if (nf > 0) G8U(0)
      if (nf > 1) G8U(1)
      if (nf > 2) G8U(2)
      if (nf > 3) G8U(3)
      if (nf > 4) G8U(4)
      if (nf > 5) G8U(5)
      if (nf > 6) G8U(6)
      if (rem & 7) {                        // one predicated partial group
        switch (nf) {
          case 0: G8M(0) break;
          case 1: G8M(1) break;
          case 2: G8M(2) break;
          case 3: G8M(3) break;
          case 4: G8M(4) break;
          case 5: G8M(5) break;
          case 6: G8M(6) break;
          default: G8M(7) break;
        }
      }
    }
  }
#undef G8U
#undef G8M

  // combine the 8 q-groups (after this every lane holds totals for its fl group)
#define CMB(a)                                                        \
  a += __shfl_xor(a, 8, 64);                                          \
  a += __shfl_xor(a, 16, 64);                                         \
  a += __shfl_xor(a, 32, 64);
  CMB(a0) CMB(a1) CMB(a2) CMB(a3) CMB(a4) CMB(a5) CMB(a6) CMB(a7)
#undef CMB

  float dvn = dinv[node];
  float4 bb0 = *(const float4*)&b[fl * 8];
  float4 bb1 = *(const float4*)&b[fl * 8 + 4];
  float v0 = fmaf(a0, dvn, bb0.x);
  float v1 = fmaf(a1, dvn, bb0.y);
  float v2 = fmaf(a2, dvn, bb0.z);
  float v3 = fmaf(a3, dvn, bb0.w);
  float v4 = fmaf(a4, dvn, bb1.x);
  float v5 = fmaf(a5, dvn, bb1.y);
  float v6 = fmaf(a6, dvn, bb1.z);
  float v7 = fmaf(a7, dvn, bb1.w);
  float s = v0 + v1 + v2 + v3 + v4 + v5 + v6 + v7;
  s += __shfl_xor(s, 1, 64);
  s += __shfl_xor(s, 2, 64);
  s += __shfl_xor(s, 4, 64);
  float mu = s * 0.015625f;  // /64
  float d0 = v0 - mu, d1 = v1 - mu, d2 = v2 - mu, d3 = v3 - mu;
  float d4 = v4 - mu, d5 = v5 - mu, d6 = v6 - mu, d7 = v7 - mu;
  float sv = d0 * d0 + d1 * d1 + d2 * d2 + d3 * d3 + d4 * d4 + d5 * d5 + d6 * d6 + d7 * d7;
  sv += __shfl_xor(sv, 1, 64);
  sv += __shfl_xor(sv, 2, 64);
  sv += __shfl_xor(sv, 4, 64);
  float rs = rsqrtf(sv * 0.015625f + LN_EPS);
  float4 gg0 = *(const float4*)&g[fl * 8];
  float4 gg1 = *(const float4*)&g[fl * 8 + 4];
  float4 t40 = *(const float4*)&tt[fl * 8];
  float4 t41 = *(const float4*)&tt[fl * 8 + 4];
  if (q < 2) {
    float4 o;
    if (q == 0) {
      o.x = fmaxf(fmaf(gg0.x * d0, rs, t40.x), 0.f);
      o.y = fmaxf(fmaf(gg0.y * d1, rs, t40.y), 0.f);
      o.z = fmaxf(fmaf(gg0.z * d2, rs, t40.z), 0.f);
      o.w = fmaxf(fmaf(gg0.w * d3, rs, t40.w), 0.f);
    } else {
      o.x = fmaxf(fmaf(gg1.x * d4, rs, t41.x), 0.f);
      o.y = fmaxf(fmaf(gg1.y * d5, rs, t41.y), 0.f);
      o.z = fmaxf(fmaf(gg1.z * d6, rs, t41.z), 0.f);
      o.w = fmaxf(fmaf(gg1.w * d7, rs, t41.w), 0.f);
    }
    *(float4*)&out[(size_t)node * 64 + fl * 8 + q * 4] = o;
  }
}

// ---------- final: logits = h @ Wf + bf ; log_softmax (thread per node, 2 nodes/thread) ----------
__global__ __launch_bounds__(256) void k_final(const float* __restrict__ h,
                                               const float* __restrict__ Wf,
                                               const float* __restrict__ bf,
                                               float* __restrict__ out, int n) {
  __shared__ float Wl[64 * 40];
  __shared__ float bl[40];
  int t = threadIdx.x;
  for (int i = t; i < 64 * 40; i += 256) Wl[i] = Wf[i];
  if (t < 40) bl[t] = bf[t];
  __syncthreads();
  int n0 = blockIdx.x * 512 + t;
  int n1 = n0 + 256;
  const bool ok0 = n0 < n, ok1 = n1 < n;
  float acc0[40], acc1[40];
#pragma unroll
  for (int c = 0; c < 40; ++c) { acc0[c] = bl[c]; acc1[c] = bl[c]; }
  const float* h0 = &h[(size_t)n0 * 64];
  const float* h1 = &h[(size_t)n1 * 64];
#pragma unroll 2
  for (int k4 = 0; k4 < 16; ++k4) {
    float4 a4 = ok0 ? *(const float4*)&h0[k4 * 4] : make_float4(0.f, 0.f, 0.f, 0.f);
    float4 c4v = ok1 ? *(const float4*)&h1[k4 * 4] : make_float4(0.f, 0.f, 0.f, 0.f);
    float av[4] = {a4.x, a4.y, a4.z, a4.w};
    float bv[4] = {c4v.x, c4v.y, c4v.z, c4v.w};
#pragma unroll
    for (int j = 0; j < 4; ++j) {
      int k = k4 * 4 + j;
#pragma unroll
      for (int c4 = 0; c4 < 10; ++c4) {
        float4 w = *(const float4*)&Wl[k * 40 + c4 * 4];  // uniform -> broadcast
        acc0[c4 * 4 + 0] = fmaf(av[j], w.x, acc0[c4 * 4 + 0]);
        acc0[c4 * 4 + 1] = fmaf(av[j], w.y, acc0[c4 * 4 + 1]);
        acc0[c4 * 4 + 2] = fmaf(av[j], w.z, acc0[c4 * 4 + 2]);
        acc0[c4 * 4 + 3] = fmaf(av[j], w.w, acc0[c4 * 4 + 3]);
        acc1[c4 * 4 + 0] = fmaf(bv[j], w.x, acc1[c4 * 4 + 0]);
        acc1[c4 * 4 + 1] = fmaf(bv[j], w.y, acc1[c4 * 4 + 1]);
        acc1[c4 * 4 + 2] = fmaf(bv[j], w.z, acc1[c4 * 4 + 2]);
        acc1[c4 * 4 + 3] = fmaf(bv[j], w.w, acc1[c4 * 4 + 3]);
      }
    }
  }
  float m0 = acc0[0], m1 = acc1[0];
#pragma unroll
  for (int c = 1; c < 40; ++c) { m0 = fmaxf(m0, acc0[c]); m1 = fmaxf(m1, acc1[c]); }
  float s0 = 0.f, s1 = 0.f;
#pragma unroll
  for (int c = 0; c < 40; ++c) { s0 += expf(acc0[c] - m0); s1 += expf(acc1[c] - m1); }
  float l0 = m0 + logf(s0);
  float l1 = m1 + logf(s1);
#pragma unroll
  for (int c4 = 0; c4 < 10; ++c4) {
    if (ok0) {
      float4 o = make_float4(acc0[c4 * 4 + 0] - l0, acc0[c4 * 4 + 1] - l0,
                             acc0[c4 * 4 + 2] - l0, acc0[c4 * 4 + 3] - l0);
      *(float4*)&out[(size_t)n0 * 40 + c4 * 4] = o;
    }
    if (ok1) {
      float4 o = make_float4(acc1[c4 * 4 + 0] - l1, acc1[c4 * 4 + 1] - l1,
                             acc1[c4 * 4 + 2] - l1, acc1[c4 * 4 + 3] - l1);
      *(float4*)&out[(size_t)n1 * 40 + c4 * 4] = o;
    }
  }
}

// ---------- launch ----------
extern "C" void kernel_launch(void* const* d_in, const int* in_sizes, int n_in,
                              void* d_out, int out_size, void* d_ws, size_t ws_size,
                              hipStream_t stream) {
  const float* x  = (const float*)d_in[0];
  const int*   ei = (const int*)d_in[1];
  const float* W1 = (const float*)d_in[2];
  const float* b1 = (const float*)d_in[3];
  const float* g1 = (const float*)d_in[4];
  const float* t1 = (const float*)d_in[5];
  const float* W2 = (const float*)d_in[6];
  const float* b2 = (const float*)d_in[7];
  const float* g2 = (const float*)d_in[8];
  const float* t2 = (const float*)d_in[9];
  const float* W3 = (const float*)d_in[10];
  const float* b3 = (const float*)d_in[11];
  const float* g3 = (const float*)d_in[12];
  const float* t3 = (const float*)d_in[13];
  const float* Wf = (const float*)d_in[14];
  const float* bf = (const float*)d_in[15];
  float* out = (float*)d_out;

  const int N = in_sizes[0] / 128;
  const int E = in_sizes[1] / 2;
  const int* src = ei;
  const int* dst = ei + E;
  const int NBUK = (N + 127) >> GRP_SHIFT;
  const int NEB  = (E + PCHUNK - 1) / PCHUNK;

  char* p = (char*)d_ws;
  auto carve = [&](size_t bytes) -> char* {
    char* r = p;
    p += (bytes + 255) & ~(size_t)255;
    return r;
  };
  int*      bcnt    = (int*)carve((size_t)NBUK * 4);
  int*      bbase   = (int*)carve((size_t)(NBUK + 1) * 4);
  int*      bcur    = (int*)carve((size_t)NBUK * 4);
  unsigned* pairs   = (unsigned*)carve((size_t)E * 4);
  int*      csr     = (int*)carve((size_t)E * 4);
  int*      offsets = (int*)carve((size_t)(N + 1) * 4);
  float*    dinv    = (float*)carve((size_t)N * 4);
  unsigned short* hs = (unsigned short*)carve((size_t)N * 64 * 2);
  float*    hA      = (float*)carve((size_t)N * 64 * 4);
  float*    hB      = (float*)carve((size_t)N * 64 * 4);
  (void)ws_size; (void)n_in; (void)out_size;

  dim3 B(256);
  dim3 B1K(1024);
  hipMemsetAsync(bcnt, 0, (size_t)NBUK * 4, stream);
  k_bucket_count<<<dim3(NEB), B1K, 0, stream>>>(dst, bcnt, E, NBUK);
  k_bucket_scan<<<dim3(1), B, 0, stream>>>(bcnt, bbase, bcur, NBUK);
  k_partition<<<dim3(NEB), B1K, 0, stream>>>(src, dst, bcur, pairs, E, NBUK);
  k_bucket_place<<<dim3(NBUK), B, 0, stream>>>(pairs, bbase, offsets, dinv, csr, N, E);

  const int GB = (N + 63) / 64;
  const int GA = (N + 3) / 4;
  const int GF = (N + 511) / 512;
  // layer 1
  gemm_scale<128><<<dim3(GB), B, 0, stream>>>(x, W1, dinv, hs, N);
  k_agg<<<dim3(GA), B, 0, stream>>>((const uint4*)hs, csr, offsets, dinv, b1, g1, t1, hA, N);
  // layer 2
  gemm_scale<64><<<dim3(GB), B, 0, stream>>>(hA, W2, dinv, hs, N);
  k_agg<<<dim3(GA), B, 0, stream>>>((const uint4*)hs, csr, offsets, dinv, b2, g2, t2, hB, N);
  // layer 3
  gemm_scale<64><<<dim3(GB), B, 0, stream>>>(hB, W3, dinv, hs, N);
  k_agg<<<dim3(GA), B, 0, stream>>>((const uint4*)hs, csr, offsets, dinv, b3, g3, t3, hA, N);
  // final projection + log_softmax
  k_final<<<dim3(GF), B, 0, stream>>>(hA, Wf, bf, out, N);
}

// Round 8
// 280.332 us; speedup vs baseline: 1.2660x; 1.2660x over previous
//
#include <hip/hip_runtime.h>
#include <math.h>
#include <stdint.h>

#define LN_EPS 1e-5f
#define GRP_SHIFT 7           // 128 nodes per bucket
#define MAXBUK 1024           // N <= 131072
#define PCHUNK 4096           // edges per partition block (1024 threads x 4)

// ---------- bf16 helpers (RNE) ----------
__device__ __forceinline__ unsigned short f2bf(float f) {
  unsigned int u = __float_as_uint(f);
  unsigned int r = u + 0x7fffu + ((u >> 16) & 1u);
  return (unsigned short)(r >> 16);
}
__device__ __forceinline__ float bfLo(unsigned v) { return __uint_as_float(v << 16); }
__device__ __forceinline__ float bfHi(unsigned v) { return __uint_as_float(v & 0xffff0000u); }

// ---------- CSR build, bucketed counting sort ----------
__global__ __launch_bounds__(1024) void k_bucket_count(const int* __restrict__ dst,
                                                       int* __restrict__ bcnt, int E, int NB) {
  __shared__ int hist[MAXBUK];
  int t = threadIdx.x;
  for (int i = t; i < NB; i += 1024) hist[i] = 0;
  __syncthreads();
  int e0 = blockIdx.x * PCHUNK;
  int e1 = min(e0 + PCHUNK, E);
#pragma unroll
  for (int j = 0; j < 4; ++j) {
    int i = e0 + t + j * 1024;
    if (i < e1) atomicAdd(&hist[dst[i] >> GRP_SHIFT], 1);
  }
  __syncthreads();
  for (int i = t; i < NB; i += 1024)
    if (hist[i]) atomicAdd(&bcnt[i], hist[i]);
}

__global__ __launch_bounds__(256) void k_bucket_scan(const int* __restrict__ cnt,
                                                     int* __restrict__ base,
                                                     int* __restrict__ cur, int NB) {
  __shared__ int ts[256];
  int t = threadIdx.x;
  int v[4];
  int s = 0;
#pragma unroll
  for (int j = 0; j < 4; ++j) { int i = t * 4 + j; v[j] = (i < NB) ? cnt[i] : 0; s += v[j]; }
  ts[t] = s;
  __syncthreads();
  for (int o = 1; o < 256; o <<= 1) {
    int x = (t >= o) ? ts[t - o] : 0;
    __syncthreads();
    ts[t] += x;
    __syncthreads();
  }
  int run = ts[t] - s;
#pragma unroll
  for (int j = 0; j < 4; ++j) {
    int i = t * 4 + j;
    if (i < NB) { base[i] = run; cur[i] = run; }
    run += v[j];
  }
  if (t == 255) base[NB] = run;  // == E
}

// partition edges into per-bucket regions; payload packed (src<<7)|dst_local (N < 2^25).
// rank within (block,bucket) captured from the first histogram atomic -> single LDS pass.
__global__ __launch_bounds__(1024) void k_partition(const int* __restrict__ src,
                                                    const int* __restrict__ dst,
                                                    int* __restrict__ bcur,
                                                    unsigned* __restrict__ pairs, int E, int NB) {
  __shared__ int hist[MAXBUK];
  __shared__ int base[MAXBUK];
  int t = threadIdx.x;
  for (int i = t; i < NB; i += 1024) hist[i] = 0;
  __syncthreads();
  int e0 = blockIdx.x * PCHUNK;
  int e1 = min(e0 + PCHUNK, E);
  int sv[4], dv[4], rk[4];
#pragma unroll
  for (int j = 0; j < 4; ++j) {
    int i = e0 + t + j * 1024;
    if (i < e1) {
      sv[j] = src[i];
      dv[j] = dst[i];
      rk[j] = atomicAdd(&hist[dv[j] >> GRP_SHIFT], 1);
    } else {
      dv[j] = -1;
    }
  }
  __syncthreads();
  for (int i = t; i < NB; i += 1024) {
    int c = hist[i];
    base[i] = c ? atomicAdd(&bcur[i], c) : 0;
  }
  __syncthreads();
#pragma unroll
  for (int j = 0; j < 4; ++j) {
    if (dv[j] >= 0) {
      int b = dv[j] >> GRP_SHIFT;
      pairs[base[b] + rk[j]] = ((unsigned)sv[j] << GRP_SHIFT) | (unsigned)(dv[j] & 127);
    }
  }
}

__global__ __launch_bounds__(256) void k_bucket_place(const unsigned* __restrict__ pairs,
                                                      const int* __restrict__ bbase,
                                                      int* __restrict__ offsets,
                                                      float* __restrict__ dinv,
                                                      int* __restrict__ csr, int N, int E) {
  __shared__ int cnt[128];
  __shared__ int sc[128];
  int t = threadIdx.x;
  int b = blockIdx.x;
  int node0 = b << GRP_SHIFT;
  if (t < 128) cnt[t] = 0;
  int beg = bbase[b], end = bbase[b + 1];
  if (b == 0 && t == 0) offsets[N] = E;
  __syncthreads();
  for (int i = beg + t; i < end; i += 256) atomicAdd(&cnt[pairs[i] & 127u], 1);
  __syncthreads();
  if (t < 128) sc[t] = cnt[t];
  __syncthreads();
  for (int o = 1; o < 128; o <<= 1) {
    int x = (t < 128 && t >= o) ? sc[t - o] : 0;
    __syncthreads();
    if (t < 128) sc[t] += x;
    __syncthreads();
  }
  if (t < 128) {
    int excl = sc[t] - cnt[t];
    int node = node0 + t;
    if (node < N) {
      offsets[node] = beg + excl;
      int d = cnt[t];
      dinv[node] = d > 0 ? rsqrtf((float)d) : 0.f;
    }
    sc[t] = beg + excl;  // becomes write cursor
  }
  __syncthreads();
  for (int i = beg + t; i < end; i += 256) {
    unsigned pk = pairs[i];
    int pos = atomicAdd(&sc[pk & 127u], 1);
    csr[pos] = (int)(pk >> GRP_SHIFT);
  }
}

// ---------- GEMM: out[m] = bf16( dinv[m] * (A[m] @ W) ), A:[M][K], W:[K][64] ----------
template <int K>
__global__ __launch_bounds__(256) void gemm_scale(const float* __restrict__ A,
                                                  const float* __restrict__ W,
                                                  const float* __restrict__ dinv,
                                                  unsigned short* __restrict__ out, int M) {
  __shared__ float xs[16][64];   // transposed A tile: xs[k][m]
  __shared__ float wsh[16][64];  // W tile: wsh[k][c]
  int t = threadIdx.x;
  int m0 = blockIdx.x * 64;
  int lm = t >> 2;
  int lk = (t & 3) << 2;
  int mr = (t & 15) << 2;
  int cc = (t >> 4) << 2;
  float acc[4][4] = {{0.f}};
  int gm = m0 + lm;
  const bool mok = gm < M;
  for (int kc = 0; kc < K; kc += 16) {
    float4 av = make_float4(0.f, 0.f, 0.f, 0.f);
    if (mok) av = *(const float4*)&A[(size_t)gm * K + kc + lk];
    float wv[4];
#pragma unroll
    for (int r = 0; r < 4; ++r) {
      int k = (t >> 6) + (r << 2);
      wv[r] = W[(size_t)(kc + k) * 64 + (t & 63)];
    }
    __syncthreads();
    xs[lk + 0][lm] = av.x;
    xs[lk + 1][lm] = av.y;
    xs[lk + 2][lm] = av.z;
    xs[lk + 3][lm] = av.w;
#pragma unroll
    for (int r = 0; r < 4; ++r) {
      int k = (t >> 6) + (r << 2);
      wsh[k][t & 63] = wv[r];
    }
    __syncthreads();
#pragma unroll
    for (int k = 0; k < 16; ++k) {
      float4 a4 = *(const float4*)&xs[k][mr];
      float4 b4 = *(const float4*)&wsh[k][cc];
      float a[4] = {a4.x, a4.y, a4.z, a4.w};
      float b[4] = {b4.x, b4.y, b4.z, b4.w};
#pragma unroll
      for (int i = 0; i < 4; ++i)
#pragma unroll
        for (int j = 0; j < 4; ++j) acc[i][j] = fmaf(a[i], b[j], acc[i][j]);
    }
  }
#pragma unroll
  for (int i = 0; i < 4; ++i) {
    int row = m0 + mr + i;
    if (row < M) {
      float sc = dinv[row];
      ushort4 o;
      o.x = f2bf(acc[i][0] * sc);
      o.y = f2bf(acc[i][1] * sc);
      o.z = f2bf(acc[i][2] * sc);
      o.w = f2bf(acc[i][3] * sc);
      *(ushort4*)&out[(size_t)row * 64 + cc] = o;
    }
  }
}

// ---------- aggregation + bias + LayerNorm + ReLU ----------
// wave per node (round-6 proven structure). lane = (q, fl): q = lane>>4 handles edge
// (16c + 4j + q); fl = lane&15 owns features 4fl..4fl+3 (uint2 = 8B = 4 bf16 per gather).
// Full 16-edge groups are unmasked adds; only the final partial group is predicated.
__global__ __launch_bounds__(256) void k_agg(const uint2* __restrict__ hs64,
                                             const int* __restrict__ csr,
                                             const int* __restrict__ offsets,
                                             const float* __restrict__ dinv,
                                             const float* __restrict__ b,
                                             const float* __restrict__ g,
                                             const float* __restrict__ tt,
                                             float* __restrict__ out, int n) {
  int lane = threadIdx.x & 63;
  int q = lane >> 4;
  int fl = lane & 15;
  int node = blockIdx.x * 4 + (threadIdx.x >> 6);
  if (node >= n) return;
  int beg = offsets[node];
  int end = offsets[node + 1];
  float a0 = 0.f, a1 = 0.f, a2 = 0.f, a3 = 0.f;

#define G4U(c)                                                          \
  {                                                                     \
    _Pragma("unroll") for (int j = 0; j < 4; ++j) {                     \
      int sj = __shfl(cs, 16 * (c) + 4 * j + q, 64);                    \
      uint2 v = hs64[(size_t)sj * 16 + fl];                             \
      a0 += bfLo(v.x); a1 += bfHi(v.x);                                 \
      a2 += bfLo(v.y); a3 += bfHi(v.y);                                 \
    }                                                                   \
  }
#define G4M(c)                                                          \
  {                                                                     \
    _Pragma("unroll") for (int j = 0; j < 4; ++j) {                     \
      int sj = __shfl(cs, 16 * (c) + 4 * j + q, 64);                    \
      uint2 v = hs64[(size_t)sj * 16 + fl];                             \
      float m = (e0 + 16 * (c) + 4 * j + q < end) ? 1.f : 0.f;          \
      a0 = fmaf(m, bfLo(v.x), a0);                                      \
      a1 = fmaf(m, bfHi(v.x), a1);                                      \
      a2 = fmaf(m, bfLo(v.y), a2);                                      \
      a3 = fmaf(m, bfHi(v.y), a3);                                      \
    }                                                                   \
  }

  for (int e0 = beg; e0 < end; e0 += 64) {
    int cs = csr[min(e0 + lane, end - 1)];  // 64 edge indices, one coalesced load
    int rem = end - e0;                     // wave-uniform
    if (rem >= 64) {
      G4U(0) G4U(1) G4U(2) G4U(3)
    } else {
      int nf = rem >> 4;                    // full 16-edge groups
      if (nf > 0) G4U(0)
      if (nf > 1) G4U(1)
      if (nf > 2) G4U(2)
      if (rem & 15) {                       // one predicated partial group
        switch (nf) {
          case 0: G4M(0) break;
          case 1: G4M(1) break;
          case 2: G4M(2) break;
          default: G4M(3) break;
        }
      }
    }
  }
#undef G4U
#undef G4M

  // combine the 4 quarters (after this every lane holds totals for its fl group)
  a0 += __shfl_xor(a0, 16, 64); a0 += __shfl_xor(a0, 32, 64);
  a1 += __shfl_xor(a1, 16, 64); a1 += __shfl_xor(a1, 32, 64);
  a2 += __shfl_xor(a2, 16, 64); a2 += __shfl_xor(a2, 32, 64);
  a3 += __shfl_xor(a3, 16, 64); a3 += __shfl_xor(a3, 32, 64);

  float dv = dinv[node];
  float4 bb = *(const float4*)&b[fl * 4];
  float v0 = fmaf(a0, dv, bb.x);
  float v1 = fmaf(a1, dv, bb.y);
  float v2 = fmaf(a2, dv, bb.z);
  float v3 = fmaf(a3, dv, bb.w);
  float s = v0 + v1 + v2 + v3;
#pragma unroll
  for (int m = 1; m < 16; m <<= 1) s += __shfl_xor(s, m, 64);
  float mu = s * 0.015625f;  // /64
  float d0 = v0 - mu, d1 = v1 - mu, d2 = v2 - mu, d3 = v3 - mu;
  float sv = d0 * d0 + d1 * d1 + d2 * d2 + d3 * d3;
#pragma unroll
  for (int m = 1; m < 16; m <<= 1) sv += __shfl_xor(sv, m, 64);
  float rs = rsqrtf(sv * 0.015625f + LN_EPS);
  float4 gg = *(const float4*)&g[fl * 4];
  float4 t4 = *(const float4*)&tt[fl * 4];
  if (q == 0) {
    float4 o;
    o.x = fmaxf(fmaf(gg.x * d0, rs, t4.x), 0.f);
    o.y = fmaxf(fmaf(gg.y * d1, rs, t4.y), 0.f);
    o.z = fmaxf(fmaf(gg.z * d2, rs, t4.z), 0.f);
    o.w = fmaxf(fmaf(gg.w * d3, rs, t4.w), 0.f);
    *(float4*)&out[(size_t)node * 64 + fl * 4] = o;
  }
}

// ---------- final: logits = h @ Wf + bf ; log_softmax (thread per node, 2 nodes/thread) ----------
__global__ __launch_bounds__(256) void k_final(const float* __restrict__ h,
                                               const float* __restrict__ Wf,
                                               const float* __restrict__ bf,
                                               float* __restrict__ out, int n) {
  __shared__ float Wl[64 * 40];
  __shared__ float bl[40];
  int t = threadIdx.x;
  for (int i = t; i < 64 * 40; i += 256) Wl[i] = Wf[i];
  if (t < 40) bl[t] = bf[t];
  __syncthreads();
  int n0 = blockIdx.x * 512 + t;
  int n1 = n0 + 256;
  const bool ok0 = n0 < n, ok1 = n1 < n;
  float acc0[40], acc1[40];
#pragma unroll
  for (int c = 0; c < 40; ++c) { acc0[c] = bl[c]; acc1[c] = bl[c]; }
  const float* h0 = &h[(size_t)n0 * 64];
  const float* h1 = &h[(size_t)n1 * 64];
#pragma unroll 2
  for (int k4 = 0; k4 < 16; ++k4) {
    float4 a4 = ok0 ? *(const float4*)&h0[k4 * 4] : make_float4(0.f, 0.f, 0.f, 0.f);
    float4 c4v = ok1 ? *(const float4*)&h1[k4 * 4] : make_float4(0.f, 0.f, 0.f, 0.f);
    float av[4] = {a4.x, a4.y, a4.z, a4.w};
    float bv[4] = {c4v.x, c4v.y, c4v.z, c4v.w};
#pragma unroll
    for (int j = 0; j < 4; ++j) {
      int k = k4 * 4 + j;
#pragma unroll
      for (int c4 = 0; c4 < 10; ++c4) {
        float4 w = *(const float4*)&Wl[k * 40 + c4 * 4];  // uniform -> broadcast
        acc0[c4 * 4 + 0] = fmaf(av[j], w.x, acc0[c4 * 4 + 0]);
        acc0[c4 * 4 + 1] = fmaf(av[j], w.y, acc0[c4 * 4 + 1]);
        acc0[c4 * 4 + 2] = fmaf(av[j], w.z, acc0[c4 * 4 + 2]);
        acc0[c4 * 4 + 3] = fmaf(av[j], w.w, acc0[c4 * 4 + 3]);
        acc1[c4 * 4 + 0] = fmaf(bv[j], w.x, acc1[c4 * 4 + 0]);
        acc1[c4 * 4 + 1] = fmaf(bv[j], w.y, acc1[c4 * 4 + 1]);
        acc1[c4 * 4 + 2] = fmaf(bv[j], w.z, acc1[c4 * 4 + 2]);
        acc1[c4 * 4 + 3] = fmaf(bv[j], w.w, acc1[c4 * 4 + 3]);
      }
    }
  }
  float m0 = acc0[0], m1 = acc1[0];
#pragma unroll
  for (int c = 1; c < 40; ++c) { m0 = fmaxf(m0, acc0[c]); m1 = fmaxf(m1, acc1[c]); }
  float s0 = 0.f, s1 = 0.f;
#pragma unroll
  for (int c = 0; c < 40; ++c) { s0 += expf(acc0[c] - m0); s1 += expf(acc1[c] - m1); }
  float l0 = m0 + logf(s0);
  float l1 = m1 + logf(s1);
#pragma unroll
  for (int c4 = 0; c4 < 10; ++c4) {
    if (ok0) {
      float4 o = make_float4(acc0[c4 * 4 + 0] - l0, acc0[c4 * 4 + 1] - l0,
                             acc0[c4 * 4 + 2] - l0, acc0[c4 * 4 + 3] - l0);
      *(float4*)&out[(size_t)n0 * 40 + c4 * 4] = o;
    }
    if (ok1) {
      float4 o = make_float4(acc1[c4 * 4 + 0] - l1, acc1[c4 * 4 + 1] - l1,
                             acc1[c4 * 4 + 2] - l1, acc1[c4 * 4 + 3] - l1);
      *(float4*)&out[(size_t)n1 * 40 + c4 * 4] = o;
    }
  }
}

// ---------- launch ----------
extern "C" void kernel_launch(void* const* d_in, const int* in_sizes, int n_in,
                              void* d_out, int out_size, void* d_ws, size_t ws_size,
                              hipStream_t stream) {
  const float* x  = (const float*)d_in[0];
  const int*   ei = (const int*)d_in[1];
  const float* W1 = (const float*)d_in[2];
  const float* b1 = (const float*)d_in[3];
  const float* g1 = (const float*)d_in[4];
  const float* t1 = (const float*)d_in[5];
  const float* W2 = (const float*)d_in[6];
  const float* b2 = (const float*)d_in[7];
  const float* g2 = (const float*)d_in[8];
  const float* t2 = (const float*)d_in[9];
  const float* W3 = (const float*)d_in[10];
  const float* b3 = (const float*)d_in[11];
  const float* g3 = (const float*)d_in[12];
  const float* t3 = (const float*)d_in[13];
  const float* Wf = (const float*)d_in[14];
  const float* bf = (const float*)d_in[15];
  float* out = (float*)d_out;

  const int N = in_sizes[0] / 128;
  const int E = in_sizes[1] / 2;
  const int* src = ei;
  const int* dst = ei + E;
  const int NBUK = (N + 127) >> GRP_SHIFT;
  const int NEB  = (E + PCHUNK - 1) / PCHUNK;

  char* p = (char*)d_ws;
  auto carve = [&](size_t bytes) -> char* {
    char* r = p;
    p += (bytes + 255) & ~(size_t)255;
    return r;
  };
  int*      bcnt    = (int*)carve((size_t)NBUK * 4);
  int*      bbase   = (int*)carve((size_t)(NBUK + 1) * 4);
  int*      bcur    = (int*)carve((size_t)NBUK * 4);
  unsigned* pairs   = (unsigned*)carve((size_t)E * 4);
  int*      csr     = (int*)carve((size_t)E * 4);
  int*      offsets = (int*)carve((size_t)(N + 1) * 4);
  float*    dinv    = (float*)carve((size_t)N * 4);
  unsigned short* hs = (unsigned short*)carve((size_t)N * 64 * 2);
  float*    hA      = (float*)carve((size_t)N * 64 * 4);
  float*    hB      = (float*)carve((size_t)N * 64 * 4);
  (void)ws_size; (void)n_in; (void)out_size;

  dim3 B(256);
  dim3 B1K(1024);
  hipMemsetAsync(bcnt, 0, (size_t)NBUK * 4, stream);
  k_bucket_count<<<dim3(NEB), B1K, 0, stream>>>(dst, bcnt, E, NBUK);
  k_bucket_scan<<<dim3(1), B, 0, stream>>>(bcnt, bbase, bcur, NBUK);
  k_partition<<<dim3(NEB), B1K, 0, stream>>>(src, dst, bcur, pairs, E, NBUK);
  k_bucket_place<<<dim3(NBUK), B, 0, stream>>>(pairs, bbase, offsets, dinv, csr, N, E);

  const int GB = (N + 63) / 64;
  const int GA = (N + 3) / 4;
  const int GF = (N + 511) / 512;
  // layer 1
  gemm_scale<128><<<dim3(GB), B, 0, stream>>>(x, W1, dinv, hs, N);
  k_agg<<<dim3(GA), B, 0, stream>>>((const uint2*)hs, csr, offsets, dinv, b1, g1, t1, hA, N);
  // layer 2
  gemm_scale<64><<<dim3(GB), B, 0, stream>>>(hA, W2, dinv, hs, N);
  k_agg<<<dim3(GA), B, 0, stream>>>((const uint2*)hs, csr, offsets, dinv, b2, g2, t2, hB, N);
  // layer 3
  gemm_scale<64><<<dim3(GB), B, 0, stream>>>(hB, W3, dinv, hs, N);
  k_agg<<<dim3(GA), B, 0, stream>>>((const uint2*)hs, csr, offsets, dinv, b3, g3, t3, hA, N);
  // final projection + log_softmax
  k_final<<<dim3(GF), B, 0, stream>>>(hA, Wf, bf, out, N);
}